// Round 1
// baseline (337.876 us; speedup 1.0000x reference)
//
#include <hip/hip_runtime.h>

#define N_T 8
#define N_CAPS 16
#define CAP_DIM 16
#define HW 4096
#define P_TILE 32
#define LDS_STRIDE 36   // 32 floats + 4 pad (keeps 16B alignment, shifts banks by 4/row)
#define EPS 1e-6f

typedef float f4_native __attribute__((ext_vector_type(4)));

// Block: 256 threads, one (b, capsule c) pair x 32 spatial positions.
// LDS: u^2 for all 128 (t,d) channels x 32 positions, padded rows = 18 KiB.
// 8 blocks/CU (LDS 8x18KiB = 144KiB <= 160KiB, 32 waves/CU) -> full occupancy.
__global__ __launch_bounds__(256, 8) void caps_norm_kernel(
    const float* __restrict__ z, const float* __restrict__ u,
    const float* __restrict__ w, const float* __restrict__ beta,
    float* __restrict__ out)
{
    __shared__ float lds[128 * LDS_STRIDE];

    const int tid = threadIdx.x;
    const int bid = blockIdx.x;            // ((b*16 + c)*128 + ptile)
    const int ptile = bid & 127;
    const int c     = (bid >> 7) & 15;
    const int b     = bid >> 11;
    const int p0    = ptile * P_TILE;

    // uniform scalars (compiler emits s_loads)
    float W9[9];
#pragma unroll
    for (int i = 0; i < 9; ++i) W9[i] = w[i];
    const float bet = beta[0];

    const size_t base_b = (size_t)b * 2048 * HW;

    // ---- stage u^2 tile into LDS + prefetch z (both before the barrier) ----
    // 128 rows x 8 float4-quads = 1024 slots, 4 per thread.
    float4 zpre[4];
#pragma unroll
    for (int k = 0; k < 4; ++k) {
        int s = tid + k * 256;             // 0..1023 float4 slots
        int r = s >> 3;                    // row = t*16 + d, 0..127
        int q = s & 7;                     // quad within row
        int t = r >> 4, d = r & 15;
        int ch = t * 256 + c * 16 + d;
        size_t g = base_b + (size_t)ch * HW + p0 + q * 4;
        const float4 v = *(const float4*)(u + g);
        zpre[k] = *(const float4*)(z + g); // prefetch: independent of LDS/barrier
        float4 sq;
        sq.x = v.x * v.x; sq.y = v.y * v.y; sq.z = v.z * v.z; sq.w = v.w * v.w;
        *(float4*)(lds + r * LDS_STRIDE + q * 4) = sq;
    }
    __syncthreads();

    // ---- compute: 9-point wrapped stencil over (t,d), then (z+beta)*rsqrt ----
#pragma unroll
    for (int k = 0; k < 4; ++k) {
        int s = tid + k * 256;
        int r = s >> 3;
        int q = s & 7;
        int t = r >> 4, d = r & 15;

        float ax = 0.f, ay = 0.f, az = 0.f, aw = 0.f;
#pragma unroll
        for (int i = 0; i < 3; ++i) {
            int tt = (t + i + 7) & 7;
#pragma unroll
            for (int j = 0; j < 3; ++j) {
                int dd = (d + j + 15) & 15;
                float ww = W9[i * 3 + j];
                const float4 a = *(const float4*)(lds + ((tt << 4) + dd) * LDS_STRIDE + q * 4);
                ax += ww * a.x; ay += ww * a.y; az += ww * a.z; aw += ww * a.w;
            }
        }

        int ch = t * 256 + c * 16 + d;
        size_t gidx = base_b + (size_t)ch * HW + p0 + q * 4;
        const float4 z4 = zpre[k];
        f4_native o;
        o.x = (z4.x + bet) * rsqrtf(ax + EPS);
        o.y = (z4.y + bet) * rsqrtf(ay + EPS);
        o.z = (z4.z + bet) * rsqrtf(az + EPS);
        o.w = (z4.w + bet) * rsqrtf(aw + EPS);
        // streaming output: keep it out of L3 so z/u stay resident across iterations
        __builtin_nontemporal_store(o, (f4_native*)(out + gidx));
    }
}

extern "C" void kernel_launch(void* const* d_in, const int* in_sizes, int n_in,
                              void* d_out, int out_size, void* d_ws, size_t ws_size,
                              hipStream_t stream) {
    const float* z    = (const float*)d_in[0];
    const float* u    = (const float*)d_in[1];
    const float* w    = (const float*)d_in[2];
    const float* beta = (const float*)d_in[3];
    float* out = (float*)d_out;

    // grid = B(4) * N_CAPS(16) * (HW/P_TILE = 128) = 8192 blocks
    caps_norm_kernel<<<dim3(8192), dim3(256), 0, stream>>>(z, u, w, beta, out);
}

// Round 2
// 321.154 us; speedup vs baseline: 1.0521x; 1.0521x over previous
//
#include <hip/hip_runtime.h>

#define N_T 8
#define N_CAPS 16
#define CAP_DIM 16
#define HW 4096
#define P_TILE 64
#define NTILES 4          // consecutive spatial tiles per block (persistent)
#define EPS 1e-6f

// Block: 256 threads, one (b, capsule c) pair x 4 consecutive 64-position tiles.
// Software pipeline: tile i+1 global loads (u,z) are in flight while tile i
// computes from LDS -> HBM stays busy through the compute phase (fixes convoy).
// LDS: double buffer 2 x 128ch x 64pos x 4B = 64 KiB -> 2 blocks/CU.
__global__ __launch_bounds__(256, 2) void caps_norm_kernel(
    const float* __restrict__ z, const float* __restrict__ u,
    const float* __restrict__ w, const float* __restrict__ beta,
    float* __restrict__ out)
{
    __shared__ float lds[2][128 * P_TILE];

    const int tid = threadIdx.x;
    const int bid = blockIdx.x;            // ((b*16 + c)*16 + pg)
    const int pg  = bid & 15;
    const int c   = (bid >> 4) & 15;
    const int b   = bid >> 8;
    const int pbase = pg * (P_TILE * NTILES);   // 256 positions per block

    float W9[9];
#pragma unroll
    for (int i = 0; i < 9; ++i) W9[i] = w[i];
    const float bet = beta[0];

    const size_t base_b = (size_t)b * 2048 * HW;

    // slot geometry: 8 float4 slots per thread; s = tid + k*256
    int RR[8], QQ[8];
    size_t GOFF[8];                        // base_b + ch*HW + q*4 (add p0 at use)
#pragma unroll
    for (int k = 0; k < 8; ++k) {
        int s = tid + (k << 8);
        int r = s >> 4, q = s & 15;        // row = t*16+d (0..127), quad (0..15)
        int t = r >> 4, d = r & 15;
        int ch = t * 256 + c * 16 + d;
        RR[k] = r; QQ[k] = q;
        GOFF[k] = base_b + (size_t)ch * HW + (size_t)(q << 2);
    }

    float4 uN[8], zA[8], zB[8];

#define STAGE_LOAD(TI, ZREG)                                                 \
    {                                                                        \
        const int p0_ = pbase + (TI) * P_TILE;                               \
        _Pragma("unroll")                                                    \
        for (int k = 0; k < 8; ++k) {                                        \
            uN[k]   = *(const float4*)(u + GOFF[k] + p0_);                   \
            ZREG[k] = *(const float4*)(z + GOFF[k] + p0_);                   \
        }                                                                    \
    }

#define SQ_WRITE(BUF)                                                        \
    {                                                                        \
        _Pragma("unroll")                                                    \
        for (int k = 0; k < 8; ++k) {                                        \
            float4 v = uN[k];                                                \
            float4 sq;                                                       \
            sq.x = v.x*v.x; sq.y = v.y*v.y; sq.z = v.z*v.z; sq.w = v.w*v.w;  \
            *(float4*)(&lds[BUF][RR[k] * P_TILE + QQ[k] * 4]) = sq;          \
        }                                                                    \
    }

#define COMPUTE(TI, BUF, ZREG)                                               \
    {                                                                        \
        const int p0_ = pbase + (TI) * P_TILE;                               \
        _Pragma("unroll")                                                    \
        for (int k = 0; k < 8; ++k) {                                        \
            int r = RR[k], q = QQ[k];                                        \
            int t = r >> 4, d = r & 15;                                      \
            float ax = 0.f, ay = 0.f, az = 0.f, aw = 0.f;                    \
            _Pragma("unroll")                                                \
            for (int i = 0; i < 3; ++i) {                                    \
                int tt = (t + i + 7) & 7;                                    \
                _Pragma("unroll")                                            \
                for (int j = 0; j < 3; ++j) {                                \
                    int dd = (d + j + 15) & 15;                              \
                    float ww = W9[i * 3 + j];                                \
                    const float4 a = *(const float4*)(                       \
                        &lds[BUF][((tt << 4) + dd) * P_TILE + q * 4]);       \
                    ax += ww*a.x; ay += ww*a.y; az += ww*a.z; aw += ww*a.w;  \
                }                                                            \
            }                                                                \
            const float4 z4 = ZREG[k];                                       \
            float4 o;                                                        \
            o.x = (z4.x + bet) * rsqrtf(ax + EPS);                           \
            o.y = (z4.y + bet) * rsqrtf(ay + EPS);                           \
            o.z = (z4.z + bet) * rsqrtf(az + EPS);                           \
            o.w = (z4.w + bet) * rsqrtf(aw + EPS);                           \
            *(float4*)(out + GOFF[k] + p0_) = o;                             \
        }                                                                    \
    }

    // ---- software pipeline over 4 consecutive spatial tiles ----
    STAGE_LOAD(0, zA)                      // tile 0 -> regs
    SQ_WRITE(0)                            // u^2 -> buf0
    __syncthreads();

    STAGE_LOAD(1, zB)                      // tile 1 loads in flight...
    COMPUTE(0, 0, zA)                      // ...while computing tile 0
    SQ_WRITE(1)                            // waits vmcnt, u^2 -> buf1
    __syncthreads();

    STAGE_LOAD(2, zA)
    COMPUTE(1, 1, zB)
    SQ_WRITE(0)
    __syncthreads();

    STAGE_LOAD(3, zB)
    COMPUTE(2, 0, zA)
    SQ_WRITE(1)
    __syncthreads();

    COMPUTE(3, 1, zB)                      // drain

#undef STAGE_LOAD
#undef SQ_WRITE
#undef COMPUTE
}

extern "C" void kernel_launch(void* const* d_in, const int* in_sizes, int n_in,
                              void* d_out, int out_size, void* d_ws, size_t ws_size,
                              hipStream_t stream) {
    const float* z    = (const float*)d_in[0];
    const float* u    = (const float*)d_in[1];
    const float* w    = (const float*)d_in[2];
    const float* beta = (const float*)d_in[3];
    float* out = (float*)d_out;

    // grid = B(4) * N_CAPS(16) * (HW / (P_TILE*NTILES) = 16) = 1024 blocks
    caps_norm_kernel<<<dim3(1024), dim3(256), 0, stream>>>(z, u, w, beta, out);
}